// Round 15
// baseline (142.902 us; speedup 1.0000x reference)
//
#include <hip/hip_runtime.h>
#include <hip/hip_bf16.h>

#define B 2
#define S 2048
#define E 1024
#define H 16
#define D 64

typedef unsigned short ushort_t;
typedef __attribute__((ext_vector_type(8))) short bf16x8;    // 8 bf16 = 4 VGPRs
typedef __attribute__((ext_vector_type(4))) float f32x4;     // 16x16 C/D frag
typedef __attribute__((ext_vector_type(16))) float f32x16;   // 32x32 C/D frag

static __device__ __forceinline__ ushort_t f2bf(float f) {
    union { float f; unsigned u; } v; v.f = f;
    unsigned r = v.u + 0x7fffu + ((v.u >> 16) & 1u);   // RNE
    return (ushort_t)(r >> 16);
}
// pack two floats into one dword of RNE-rounded bf16 pair: [hi16(f1):hi16(f0)]
static __device__ __forceinline__ unsigned pack2bf(float f0, float f1) {
    unsigned u0 = __float_as_uint(f0), u1 = __float_as_uint(f1);
    u0 += 0x7fffu + ((u0 >> 16) & 1u);
    u1 += 0x7fffu + ((u1 >> 16) & 1u);
    return __builtin_amdgcn_perm(u1, u0, 0x07060302u);
}

#define MFMA(a, b, c)   __builtin_amdgcn_mfma_f32_16x16x32_bf16((a), (b), (c), 0, 0, 0)
#define MFMA32(a, b, c) __builtin_amdgcn_mfma_f32_32x32x16_bf16((a), (b), (c), 0, 0, 0)
#define PACKBF(hi, lo) __builtin_amdgcn_perm((hi), (lo), 0x07060302u)
#define WQSCALE 0.18033688011112042f   // 0.125 * log2(e)
// LDS-only barrier: waits ds ops, leaves global prefetch loads in flight.
#define LBAR() do { asm volatile("s_waitcnt lgkmcnt(0)" ::: "memory"); \
                    __builtin_amdgcn_s_barrier(); } while (0)

// softmax of one 32-row E^T sub-tile -> two packed PV A-frags (paA, paB)
#define SOFTMAX_PACK(e, paA, paB) do {                                          \
    unsigned pt[16];                                                            \
    _Pragma("unroll")                                                           \
    for (int r = 0; r < 16; r += 2) {                                           \
        float pe0 = __builtin_amdgcn_exp2f((e)[r]);                             \
        float pe1 = __builtin_amdgcn_exp2f((e)[r + 1]);                         \
        ls2.x += pe0; ls2.y += pe1;                                             \
        pt[r]     = __float_as_uint(pe0);                                       \
        pt[r + 1] = __float_as_uint(pe1);                                       \
    }                                                                           \
    {                                                                           \
        unsigned dA = PACKBF(pt[1], pt[0]), dB = PACKBF(pt[3], pt[2]);          \
        unsigned dC = PACKBF(pt[5], pt[4]), dD = PACKBF(pt[7], pt[6]);          \
        asm volatile("v_permlane32_swap_b32 %0, %1" : "+v"(dA), "+v"(dC));      \
        asm volatile("v_permlane32_swap_b32 %0, %1" : "+v"(dB), "+v"(dD));      \
        (paA).u[0] = dA; (paA).u[1] = dB; (paA).u[2] = dC; (paA).u[3] = dD;     \
    }                                                                           \
    {                                                                           \
        unsigned dA = PACKBF(pt[9],  pt[8]),  dB = PACKBF(pt[11], pt[10]);      \
        unsigned dC = PACKBF(pt[13], pt[12]), dD = PACKBF(pt[15], pt[14]);      \
        asm volatile("v_permlane32_swap_b32 %0, %1" : "+v"(dA), "+v"(dC));      \
        asm volatile("v_permlane32_swap_b32 %0, %1" : "+v"(dB), "+v"(dD));      \
        (paB).u[0] = dA; (paB).u[1] = dB; (paB).u[2] = dC; (paB).u[3] = dD;     \
    }                                                                           \
} while (0)

// ---------------- Kernel 1: QKV projection (vectorized pack staging, R21) ----------------
__global__ __launch_bounds__(256) void qkv_proj(
    const float* __restrict__ x,
    const float* __restrict__ Wq, const float* __restrict__ Wk, const float* __restrict__ Wv,
    const float* __restrict__ Wo,
    ushort_t* __restrict__ q, ushort_t* __restrict__ k, ushort_t* __restrict__ vT,
    ushort_t* __restrict__ wob)
{
    __shared__ ushort_t Xs[64][72];
    __shared__ ushort_t Wqs[64][72], Wks[64][72], Wvs[64][72];
    int t = threadIdx.x;
    int bh = blockIdx.y, b = bh >> 4, h = bh & 15;
    int s0 = blockIdx.x * 64;
    {   // fused Wo fp32 -> bf16 (1024 blocks x 1024 elems), packed 8B store
        int woid = blockIdx.y * 32 + blockIdx.x;
        int i = woid * 1024 + t * 4;
        float4 f = *(const float4*)(Wo + i);
        unsigned w0 = pack2bf(f.x, f.y), w1 = pack2bf(f.z, f.w);
        uint2 u2; u2.x = w0; u2.y = w1;
        *(uint2*)(wob + i) = u2;
    }
    int i_ = t >> 2, d0_ = (t & 3) * 16;
    {   // stage x (64 s x 64 d) fp32 -> bf16, packed b128 stores
        const float* xp = x + ((size_t)(b * S + s0 + i_)) * E + h * D + d0_;
        unsigned xw[8];
        #pragma unroll
        for (int c = 0; c < 4; c++) {
            float4 f = *(const float4*)(xp + c * 4);
            xw[c * 2]     = pack2bf(f.x, f.y);
            xw[c * 2 + 1] = pack2bf(f.z, f.w);
        }
        *(bf16x8*)&Xs[i_][d0_]     = *(bf16x8*)&xw[0];
        *(bf16x8*)&Xs[i_][d0_ + 8] = *(bf16x8*)&xw[4];
    }
    {   // stage weights fp32 -> bf16 (Wq pre-scaled), packed b128 stores
        const float* wqp = Wq + i_ * 64 + d0_;
        const float* wkp = Wk + i_ * 64 + d0_;
        const float* wvp = Wv + i_ * 64 + d0_;
        unsigned ww[8];
        #pragma unroll
        for (int c = 0; c < 4; c++) {
            float4 f = *(const float4*)(wqp + c * 4);
            ww[c * 2]     = pack2bf(f.x * WQSCALE, f.y * WQSCALE);
            ww[c * 2 + 1] = pack2bf(f.z * WQSCALE, f.w * WQSCALE);
        }
        *(bf16x8*)&Wqs[i_][d0_]     = *(bf16x8*)&ww[0];
        *(bf16x8*)&Wqs[i_][d0_ + 8] = *(bf16x8*)&ww[4];
        #pragma unroll
        for (int c = 0; c < 4; c++) {
            float4 f = *(const float4*)(wkp + c * 4);
            ww[c * 2]     = pack2bf(f.x, f.y);
            ww[c * 2 + 1] = pack2bf(f.z, f.w);
        }
        *(bf16x8*)&Wks[i_][d0_]     = *(bf16x8*)&ww[0];
        *(bf16x8*)&Wks[i_][d0_ + 8] = *(bf16x8*)&ww[4];
        #pragma unroll
        for (int c = 0; c < 4; c++) {
            float4 f = *(const float4*)(wvp + c * 4);
            ww[c * 2]     = pack2bf(f.x, f.y);
            ww[c * 2 + 1] = pack2bf(f.z, f.w);
        }
        *(bf16x8*)&Wvs[i_][d0_]     = *(bf16x8*)&ww[0];
        *(bf16x8*)&Wvs[i_][d0_ + 8] = *(bf16x8*)&ww[4];
    }
    __syncthreads();
    int w = t >> 6, lane = t & 63, m = lane & 15, quad = lane >> 4;
    bf16x8 a0 = *(bf16x8*)&Xs[16 * w + m][quad * 8];
    bf16x8 a1 = *(bf16x8*)&Xs[16 * w + m][32 + quad * 8];
    f32x4 cq[4], ck[4], cv[4];
    #pragma unroll
    for (int nt = 0; nt < 4; nt++) { cq[nt] = (f32x4)0.f; ck[nt] = (f32x4)0.f; cv[nt] = (f32x4)0.f; }
    #pragma unroll
    for (int nt = 0; nt < 4; nt++) {
        bf16x8 b0, b1;
        b0 = *(bf16x8*)&Wqs[nt * 16 + m][quad * 8]; b1 = *(bf16x8*)&Wqs[nt * 16 + m][32 + quad * 8];
        cq[nt] = MFMA(a0, b0, cq[nt]); cq[nt] = MFMA(a1, b1, cq[nt]);
        b0 = *(bf16x8*)&Wks[nt * 16 + m][quad * 8]; b1 = *(bf16x8*)&Wks[nt * 16 + m][32 + quad * 8];
        ck[nt] = MFMA(a0, b0, ck[nt]); ck[nt] = MFMA(a1, b1, ck[nt]);
        b0 = *(bf16x8*)&Wvs[nt * 16 + m][quad * 8]; b1 = *(bf16x8*)&Wvs[nt * 16 + m][32 + quad * 8];
        cv[nt] = MFMA(a0, b0, cv[nt]); cv[nt] = MFMA(a1, b1, cv[nt]);
    }
    size_t base = (size_t)bh * S + s0;
    #pragma unroll
    for (int nt = 0; nt < 4; nt++)
        #pragma unroll
        for (int r = 0; r < 4; r++) {
            size_t idx = (base + 16 * w + quad * 4 + r) * D + nt * 16 + m;
            q[idx] = f2bf(cq[nt][r]);
            k[idx] = f2bf(ck[nt][r]);
        }
    __syncthreads();
    #pragma unroll
    for (int nt = 0; nt < 4; nt++) {   // v transpose: packed b64 store per nt
        unsigned v0 = pack2bf(cv[nt][0], cv[nt][1]);
        unsigned v1 = pack2bf(cv[nt][2], cv[nt][3]);
        uint2 u2; u2.x = v0; u2.y = v1;
        *(uint2*)&Wvs[nt * 16 + m][16 * w + quad * 4] = u2;
    }
    __syncthreads();
    {
        int d0 = t >> 2, sc = (t & 3) * 16;
        ushort_t* vp = vT + ((size_t)bh * D + d0) * S + s0 + sc;
        *(bf16x8*)(vp)     = *(bf16x8*)&Wvs[d0][sc];
        *(bf16x8*)(vp + 8) = *(bf16x8*)&Wvs[d0][sc + 8];
    }
}

// ---------------- Kernel 2: flash attention (R23: V-hoist + launch_bounds(512,3)) ----------------
// Budget model (R14): timed region = 2x45us fills (harness) + flash 44.9 + ~7us rest.
// Flash is the ONLY lever. R19's V-hoist spilled because (512,4) made the allocator
// snap to the 64-VGPR cliff. LDS (73.7KB) caps occupancy at 2 blocks/CU for any
// VGPR <= 128, so (512,3) (VGPR budget ~170) lets the allocator use ~90-110 real
// registers for the hoisted V frags WITHOUT changing occupancy and WITHOUT spill.
// Key counters: VGPR_Count > 64 means hoist took; WRITE_SIZE ~8.2MB means no spill.
__global__ __launch_bounds__(512, 3) void flash_attn(
    const ushort_t* __restrict__ q, const ushort_t* __restrict__ k,
    const ushort_t* __restrict__ vT, ushort_t* __restrict__ ao)
{
    __shared__ ushort_t Ks[2][2][64][72];   // [grp][buf][s_local][d]
    __shared__ ushort_t Vt[2][2][64][72];   // [grp][buf][d][s_local]
    int t = threadIdx.x;
    int lin = blockIdx.x;                   // 512 blocks, 1-D
    int xcd = lin & 7, loc = lin >> 3;      // XCD round-robin %8
    int bh = xcd * 4 + (loc >> 4);          // 4 bh per XCD (2 MB K/V <= 4 MB L2)
    int q0 = (loc & 15) * 128;              // 16 q-tiles per bh
    int b = bh >> 4, h = bh & 15;
    int w = t >> 6, lane = t & 63, l31 = lane & 31, half = lane >> 5;
    int g = w >> 2, wq = w & 3;             // kv-split group, q-row wave
    int tg = t & 255;                       // staging id within group

    const ushort_t* qb = q + ((size_t)bh * S + q0) * D;
    const ushort_t* kb = k + (size_t)bh * S * D;
    const ushort_t* vb = vT + (size_t)bh * D * S;

    bf16x8 qf[4];
    {
        const ushort_t* qp = qb + (size_t)(wq * 32 + l31) * D + half * 8;
        #pragma unroll
        for (int c = 0; c < 4; c++) qf[c] = *(const bf16x8*)(qp + c * 16);
    }

    f32x16 o0 = (f32x16)0.f, o1 = (f32x16)0.f;
    float2 ls2 = make_float2(0.f, 0.f);

    int sr = tg >> 2, scc = (tg & 3) * 16;
    bf16x8 kp0, kp1, vp0, vp1;

    {
        int k00 = g * 64;
        const ushort_t* kp = kb + (size_t)(k00 + sr) * D + scc;
        const ushort_t* vp = vb + (size_t)sr * S + k00 + scc;
        kp0 = *(const bf16x8*)(kp);     kp1 = *(const bf16x8*)(kp + 8);
        vp0 = *(const bf16x8*)(vp);     vp1 = *(const bf16x8*)(vp + 8);
        *(bf16x8*)&Ks[g][0][sr][scc]     = kp0;
        *(bf16x8*)&Ks[g][0][sr][scc + 8] = kp1;
        *(bf16x8*)&Vt[g][0][sr][scc]     = vp0;
        *(bf16x8*)&Vt[g][0][sr][scc + 8] = vp1;
    }
    LBAR();
    {
        int k01 = (2 + g) * 64;
        const ushort_t* kp = kb + (size_t)(k01 + sr) * D + scc;
        const ushort_t* vp = vb + (size_t)sr * S + k01 + scc;
        kp0 = *(const bf16x8*)(kp);     kp1 = *(const bf16x8*)(kp + 8);
        vp0 = *(const bf16x8*)(vp);     vp1 = *(const bf16x8*)(vp + 8);
    }

    const int NJ = S / 128;   // 16 tiles per group (global tile = 2*jt + g)
    for (int jt = 0; jt < NJ; jt++) {
        int p = jt & 1;
        if (jt + 1 < NJ) {
            *(bf16x8*)&Ks[g][1 - p][sr][scc]     = kp0;
            *(bf16x8*)&Ks[g][1 - p][sr][scc + 8] = kp1;
            *(bf16x8*)&Vt[g][1 - p][sr][scc]     = vp0;
            *(bf16x8*)&Vt[g][1 - p][sr][scc + 8] = vp1;
        }
        if (jt + 2 < NJ) {
            int k0n = (2 * (jt + 2) + g) * 64;
            const ushort_t* kp = kb + (size_t)(k0n + sr) * D + scc;
            const ushort_t* vp = vb + (size_t)sr * S + k0n + scc;
            kp0 = *(const bf16x8*)(kp);     kp1 = *(const bf16x8*)(kp + 8);
            vp0 = *(const bf16x8*)(vp);     vp1 = *(const bf16x8*)(vp + 8);
        }

        union pu { unsigned u[4]; bf16x8 v; } pa[4];

        // ---- QK^T sub-tile 0 ----
        f32x16 e0 = (f32x16)0.f;
        __builtin_amdgcn_s_setprio(1);
        #pragma unroll
        for (int c = 0; c < 4; c++) {
            bf16x8 ka = *(bf16x8*)&Ks[g][p][l31][c * 16 + half * 8];
            e0 = MFMA32(ka, qf[c], e0);
        }
        __builtin_amdgcn_s_setprio(0);

        // ---- hoist all 8 V frags for this tile (latency covered by softmax) ----
        bf16x8 vflo[4], vfhi[4];
        #pragma unroll
        for (int kc = 0; kc < 4; kc++) {
            vflo[kc] = *(bf16x8*)&Vt[g][p][l31][kc * 16 + half * 8];
            vfhi[kc] = *(bf16x8*)&Vt[g][p][32 + l31][kc * 16 + half * 8];
        }

        SOFTMAX_PACK(e0, pa[0], pa[1]);

        // ---- QK^T sub-tile 1 ----
        f32x16 e1 = (f32x16)0.f;
        __builtin_amdgcn_s_setprio(1);
        #pragma unroll
        for (int c = 0; c < 4; c++) {
            bf16x8 ka = *(bf16x8*)&Ks[g][p][32 + l31][c * 16 + half * 8];
            e1 = MFMA32(ka, qf[c], e1);
        }
        __builtin_amdgcn_s_setprio(0);

        SOFTMAX_PACK(e1, pa[2], pa[3]);

        // ---- O += P V : operands already in registers ----
        __builtin_amdgcn_s_setprio(1);
        #pragma unroll
        for (int kc = 0; kc < 4; kc++) {
            o0 = MFMA32(pa[kc].v, vflo[kc], o0);
            o1 = MFMA32(pa[kc].v, vfhi[kc], o1);
        }
        __builtin_amdgcn_s_setprio(0);
        LBAR();   // LDS-only: prefetch loads NOT drained here
    }

    float lsum = ls2.x + ls2.y;
    float* cmb = (float*)&Ks[0][0][0][0];
    int slot = (wq * 64 + lane) * 33;
    if (g == 1) {
        #pragma unroll
        for (int r2 = 0; r2 < 16; r2++) { cmb[slot + r2] = o0[r2]; cmb[slot + 16 + r2] = o1[r2]; }
        cmb[slot + 32] = lsum;
    }
    __syncthreads();
    if (g == 0) {
        #pragma unroll
        for (int r2 = 0; r2 < 16; r2++) { o0[r2] += cmb[slot + r2]; o1[r2] += cmb[slot + 16 + r2]; }
        lsum += cmb[slot + 32];
        float lfull = lsum + __shfl_xor(lsum, 32, 64);
        float inv = 1.001953125f / lfull;
        #pragma unroll
        for (int reg = 0; reg < 16; reg++) {
            int qrow = (reg & 3) + 8 * (reg >> 2) + 4 * half;
            float li = __shfl(inv, qrow, 64);
            int srow = q0 + wq * 32 + qrow;
            size_t base2 = ((size_t)(b * S + srow)) * E + h * D + l31;
            ao[base2]      = f2bf(o0[reg] * li);
            ao[base2 + 32] = f2bf(o1[reg] * li);
        }
    }
}

// ---------------- Kernel 3: output projection (exact R17, LDS-staged A) ----------------
__global__ __launch_bounds__(512) void out_proj(
    const ushort_t* __restrict__ A, const ushort_t* __restrict__ Wob,
    const float* __restrict__ bo, float* __restrict__ Y)
{
    __shared__ ushort_t As[2][128][72];
    __shared__ ushort_t Ws[2][64][72];
    int t = threadIdx.x;
    int hwb = blockIdx.x;
    int swz = (hwb & 7) * 64 + (hwb >> 3);
    int n0 = (swz & 15) * 64, m0 = (swz >> 4) * 128;
    int w = t >> 6, lane = t & 63, m = lane & 15, quad = lane >> 4;
    f32x4 acc[4];
    #pragma unroll
    for (int nt = 0; nt < 4; nt++) acc[nt] = (f32x4)0.f;
    int ar = t >> 2, ac = (t & 3) * 16;
    int wr = t >> 3, wc = (t & 7) * 8;
    const ushort_t* apb = A + (size_t)(m0 + ar) * E + ac;
    const ushort_t* wpb = Wob + (size_t)(n0 + wr) * E + wc;
    bf16x8 arg[2], wrg;
    {
        *(bf16x8*)&As[0][ar][ac]     = *(const bf16x8*)(apb);
        *(bf16x8*)&As[0][ar][ac + 8] = *(const bf16x8*)(apb + 8);
        *(bf16x8*)&Ws[0][wr][wc]     = *(const bf16x8*)(wpb);
    }
    LBAR();
    {
        arg[0] = *(const bf16x8*)(apb + 64);
        arg[1] = *(const bf16x8*)(apb + 64 + 8);
        wrg    = *(const bf16x8*)(wpb + 64);
    }
    const int KT = E / 64;
    for (int ks = 0; ks < KT; ks++) {
        int p = ks & 1;
        if (ks + 1 < KT) {
            *(bf16x8*)&As[1 - p][ar][ac]     = arg[0];
            *(bf16x8*)&As[1 - p][ar][ac + 8] = arg[1];
            *(bf16x8*)&Ws[1 - p][wr][wc]     = wrg;
        }
        if (ks + 2 < KT) {
            int off = (ks + 2) * 64;
            arg[0] = *(const bf16x8*)(apb + off);
            arg[1] = *(const bf16x8*)(apb + off + 8);
            wrg    = *(const bf16x8*)(wpb + off);
        }
        #pragma unroll
        for (int h2 = 0; h2 < 2; h2++) {
            bf16x8 af = *(bf16x8*)&As[p][w * 16 + m][h2 * 32 + quad * 8];
            #pragma unroll
            for (int nt = 0; nt < 4; nt++) {
                bf16x8 bfr = *(bf16x8*)&Ws[p][nt * 16 + m][h2 * 32 + quad * 8];
                acc[nt] = MFMA(af, bfr, acc[nt]);
            }
        }
        LBAR();
    }
    #pragma unroll
    for (int nt = 0; nt < 4; nt++)
        #pragma unroll
        for (int r = 0; r < 4; r++) {
            int row = m0 + w * 16 + quad * 4 + r;
            int col = n0 + nt * 16 + m;
            Y[(size_t)row * E + col] = acc[nt][r] + bo[col];
        }
}

extern "C" void kernel_launch(void* const* d_in, const int* in_sizes, int n_in,
                              void* d_out, int out_size, void* d_ws, size_t ws_size,
                              hipStream_t stream)
{
    const float* x  = (const float*)d_in[0];
    const float* Wq = (const float*)d_in[1];
    const float* Wk = (const float*)d_in[2];
    const float* Wv = (const float*)d_in[3];
    const float* Wo = (const float*)d_in[4];
    const float* bo = (const float*)d_in[5];
    float* Y = (float*)d_out;

    const size_t n = (size_t)B * H * S * D;    // 4M elems
    ushort_t* qw  = (ushort_t*)d_ws;           // 8 MB
    ushort_t* kw  = qw + n;                    // 8 MB
    ushort_t* vTw = kw + n;                    // 8 MB  [bh][d][s]
    ushort_t* ao  = vTw + n;                   // 8 MB  (B,S,E)
    ushort_t* wob = ao + n;                    // 2 MB

    qkv_proj<<<dim3(S / 64, B * H), 256, 0, stream>>>(x, Wq, Wk, Wv, Wo, qw, kw, vTw, wob);
    flash_attn<<<dim3((S / 128) * B * H), 512, 0, stream>>>(qw, kw, vTw, ao);
    out_proj<<<dim3(512), 512, 0, stream>>>(ao, wob, bo, Y);
}